// Round 18
// baseline (59.933 us; speedup 1.0000x reference)
//
#include <hip/hip_runtime.h>

// Problem constants (fixed by the reference)
constexpr int N    = 16384;
constexpr int K    = 32;
constexpr int D    = 128;
constexpr int SPAD = K + 2;       // LDS score row stride (34)

typedef float f4 __attribute__((ext_vector_type(4)));

// ---- DPP helpers: butterfly reduce over 16-lane groups, pure VALU ----
template <int CTRL>
__device__ __forceinline__ float dpp_add(float v) {
    int j = __builtin_amdgcn_update_dpp(0, __float_as_int(v), CTRL, 0xF, 0xF, false);
    return v + __int_as_float(j);
}
template <int CTRL>
__device__ __forceinline__ float dpp_max(float v) {
    int j = __builtin_amdgcn_update_dpp(0, __float_as_int(v), CTRL, 0xF, 0xF, false);
    return fmaxf(v, __int_as_float(j));
}
__device__ __forceinline__ float sum16(float v) {
    v = dpp_add<0xB1>(v);
    v = dpp_add<0x4E>(v);
    v = dpp_add<0x141>(v);
    v = dpp_add<0x140>(v);
    return v;
}
__device__ __forceinline__ float max16(float v) {
    v = dpp_max<0xB1>(v);
    v = dpp_max<0x4E>(v);
    v = dpp_max<0x141>(v);
    v = dpp_max<0x140>(v);
    return v;
}

// ------------------------------------------------------------------
// Stage 1: cooperative async-prefetch pipeline.
// grid=512, 32 rows/block, 4 chunks of 8 rows. x chunk (4 KB) staged
// into double-buffered LDS; each thread prefetches ONE float4 of the
// next chunk (4 VGPR, not 64) while computing the current one.
// Compute reads x from LDS (16-B lane stride: conflict-free;
// kg-duplicated addresses broadcast).
// ------------------------------------------------------------------
__global__ __launch_bounds__(256, 4) void enc_partial(
    const float* __restrict__ x,      // (N, D)
    const float* __restrict__ codes,  // (K, D)
    const float* __restrict__ scale,  // (K,)
    float* __restrict__ ws)           // (512, K*D)
{
    __shared__ float xs[2][8][D];          // 8 KB x tile, double-buffered
    __shared__ float sc_lds[2][8][SPAD];
    __shared__ float w_lds[2][8][SPAD];
    __shared__ float cn2_lds[K];

    const int tid = threadIdx.x;
    const int kg  = tid >> 4;
    const int dg  = tid & 15;
    const int d4  = dg << 2;
    const int k0  = kg << 1;

    const float4* xg4 = reinterpret_cast<const float4*>(x + (long)blockIdx.x * 32 * D);
    float4* xs40 = reinterpret_cast<float4*>(&xs[0][0][0]);
    float4* xs41 = reinterpret_cast<float4*>(&xs[1][0][0]);

    // ---- prologue: issue chunk-0 load, hide some latency under cn2 ----
    float4 pf = xg4[tid];

    const float4 cA0 = *reinterpret_cast<const float4*>(&codes[k0 * D + d4]);
    const float4 cA1 = *reinterpret_cast<const float4*>(&codes[k0 * D + 64 + d4]);
    const float4 cB0 = *reinterpret_cast<const float4*>(&codes[(k0 + 1) * D + d4]);
    const float4 cB1 = *reinterpret_cast<const float4*>(&codes[(k0 + 1) * D + 64 + d4]);
    {
        float pa = 0.f, pb = 0.f;
        pa = fmaf(cA0.x, cA0.x, pa); pa = fmaf(cA0.y, cA0.y, pa);
        pa = fmaf(cA0.z, cA0.z, pa); pa = fmaf(cA0.w, cA0.w, pa);
        pa = fmaf(cA1.x, cA1.x, pa); pa = fmaf(cA1.y, cA1.y, pa);
        pa = fmaf(cA1.z, cA1.z, pa); pa = fmaf(cA1.w, cA1.w, pa);
        pb = fmaf(cB0.x, cB0.x, pb); pb = fmaf(cB0.y, cB0.y, pb);
        pb = fmaf(cB0.z, cB0.z, pb); pb = fmaf(cB0.w, cB0.w, pb);
        pb = fmaf(cB1.x, cB1.x, pb); pb = fmaf(cB1.y, cB1.y, pb);
        pb = fmaf(cB1.z, cB1.z, pb); pb = fmaf(cB1.w, cB1.w, pb);
        float cn2A = sum16(pa);
        float cn2B = sum16(pb);
        if (dg == 0) {
            cn2_lds[k0]     = cn2A;
            cn2_lds[k0 + 1] = cn2B;
        }
    }
    const float sclq = scale[tid & 31];

    xs40[tid] = pf;              // chunk 0 -> xs[0]
    pf = xg4[256 + tid];         // issue chunk 1
    __syncthreads();             // xs[0] + cn2 ready

    float4 tA0 = make_float4(0.f, 0.f, 0.f, 0.f);
    float4 tA1 = tA0, tB0 = tA0, tB1 = tA0;
    float swA = 0.f, swB = 0.f;

    auto PHASE1 = [&](int p) {
        #pragma unroll
        for (int n = 0; n < 8; ++n) {
            const float4 xa  = *reinterpret_cast<const float4*>(&xs[p][n][d4]);
            const float4 xb4 = *reinterpret_cast<const float4*>(&xs[p][n][64 + d4]);
            float nx = 0.f, dA = 0.f, dB = 0.f;
            nx = fmaf(xa.x, xa.x, nx);   nx = fmaf(xa.y, xa.y, nx);
            nx = fmaf(xa.z, xa.z, nx);   nx = fmaf(xa.w, xa.w, nx);
            nx = fmaf(xb4.x, xb4.x, nx); nx = fmaf(xb4.y, xb4.y, nx);
            nx = fmaf(xb4.z, xb4.z, nx); nx = fmaf(xb4.w, xb4.w, nx);
            dA = fmaf(xa.x, cA0.x, dA);  dA = fmaf(xa.y, cA0.y, dA);
            dA = fmaf(xa.z, cA0.z, dA);  dA = fmaf(xa.w, cA0.w, dA);
            dA = fmaf(xb4.x, cA1.x, dA); dA = fmaf(xb4.y, cA1.y, dA);
            dA = fmaf(xb4.z, cA1.z, dA); dA = fmaf(xb4.w, cA1.w, dA);
            dB = fmaf(xa.x, cB0.x, dB);  dB = fmaf(xa.y, cB0.y, dB);
            dB = fmaf(xa.z, cB0.z, dB);  dB = fmaf(xa.w, cB0.w, dB);
            dB = fmaf(xb4.x, cB1.x, dB); dB = fmaf(xb4.y, cB1.y, dB);
            dB = fmaf(xb4.z, cB1.z, dB); dB = fmaf(xb4.w, cB1.w, dB);
            float qA = fmaf(-2.f, dA, nx);
            float qB = fmaf(-2.f, dB, nx);
            qA = sum16(qA);
            qB = sum16(qB);
            if (dg == 0) {
                sc_lds[p][n][k0]     = qA;
                sc_lds[p][n][k0 + 1] = qB;
            }
        }
    };

    auto SOFTMAX = [&](int p) {
        const int row = tid >> 5;
        const int q   = tid & 31;
        float sq = sc_lds[p][row][q];
        float s  = sqrtf(fmaxf(sq + cn2_lds[q], 0.f)) * sclq;
        float m = max16(s);
        m = fmaxf(m, __shfl_xor(m, 16));
        float e = exp2f((s - m) * 1.44269504088896f);
        float sum = sum16(e);
        sum += __shfl_xor(sum, 16);
        w_lds[p][row][q] = e * (1.0f / sum);
    };

    auto PHASE2 = [&](int p) {
        #pragma unroll
        for (int n = 0; n < 8; ++n) {
            const float2 w = *reinterpret_cast<const float2*>(&w_lds[p][n][k0]);
            const float4 xa  = *reinterpret_cast<const float4*>(&xs[p][n][d4]);
            const float4 xb4 = *reinterpret_cast<const float4*>(&xs[p][n][64 + d4]);
            tA0.x = fmaf(w.x, xa.x, tA0.x);
            tA0.y = fmaf(w.x, xa.y, tA0.y);
            tA0.z = fmaf(w.x, xa.z, tA0.z);
            tA0.w = fmaf(w.x, xa.w, tA0.w);
            tA1.x = fmaf(w.x, xb4.x, tA1.x);
            tA1.y = fmaf(w.x, xb4.y, tA1.y);
            tA1.z = fmaf(w.x, xb4.z, tA1.z);
            tA1.w = fmaf(w.x, xb4.w, tA1.w);
            tB0.x = fmaf(w.y, xa.x, tB0.x);
            tB0.y = fmaf(w.y, xa.y, tB0.y);
            tB0.z = fmaf(w.y, xa.z, tB0.z);
            tB0.w = fmaf(w.y, xa.w, tB0.w);
            tB1.x = fmaf(w.y, xb4.x, tB1.x);
            tB1.y = fmaf(w.y, xb4.y, tB1.y);
            tB1.z = fmaf(w.y, xb4.z, tB1.z);
            tB1.w = fmaf(w.y, xb4.w, tB1.w);
            swA += w.x;
            swB += w.y;
        }
    };

    // ---- chunk 0 (p=0); pf holds chunk 1 ----
    PHASE1(0);
    __syncthreads();
    xs41[tid] = pf;              // chunk 1 -> xs[1]
    SOFTMAX(0);
    pf = xg4[512 + tid];         // issue chunk 2
    __syncthreads();
    PHASE2(0);

    // ---- chunk 1 (p=1); pf holds chunk 2 ----
    PHASE1(1);
    __syncthreads();
    xs40[tid] = pf;              // chunk 2 -> xs[0]
    SOFTMAX(1);
    pf = xg4[768 + tid];         // issue chunk 3
    __syncthreads();
    PHASE2(1);

    // ---- chunk 2 (p=0); pf holds chunk 3 ----
    PHASE1(0);
    __syncthreads();
    xs41[tid] = pf;              // chunk 3 -> xs[1]
    SOFTMAX(0);
    __syncthreads();
    PHASE2(0);

    // ---- chunk 3 (p=1) ----
    PHASE1(1);
    __syncthreads();
    SOFTMAX(1);
    __syncthreads();
    PHASE2(1);

    // ---- Epilogue: plain cached stores (keep ws in L2/L3) ----
    float* o = ws + (long)blockIdx.x * (K * D) + k0 * D + d4;
    *reinterpret_cast<float4*>(o)       = make_float4(tA0.x - swA * cA0.x, tA0.y - swA * cA0.y,
                                                      tA0.z - swA * cA0.z, tA0.w - swA * cA0.w);
    *reinterpret_cast<float4*>(o + 64)  = make_float4(tA1.x - swA * cA1.x, tA1.y - swA * cA1.y,
                                                      tA1.z - swA * cA1.z, tA1.w - swA * cA1.w);
    *reinterpret_cast<float4*>(o + 128) = make_float4(tB0.x - swB * cB0.x, tB0.y - swB * cB0.y,
                                                      tB0.z - swB * cB0.z, tB0.w - swB * cB0.w);
    *reinterpret_cast<float4*>(o + 192) = make_float4(tB1.x - swB * cB1.x, tB1.y - swB * cB1.y,
                                                      tB1.z - swB * cB1.z, tB1.w - swB * cB1.w);
}

// ------------------------------------------------------------------
// Stage 2: identical to round 14 (plain cached loads, unroll ILP).
// ------------------------------------------------------------------
__global__ __launch_bounds__(256) void reduce2(
    const float* __restrict__ ws, float* __restrict__ out, int nrows)
{
    __shared__ f4 part[64][4];

    const int tid   = threadIdx.x;
    const int col   = tid & 3;
    const int slice = tid >> 2;                  // 0..63
    const int gcol  = blockIdx.x * 4 + col;      // 0..1023
    const int rpt   = nrows >> 6;                // rows per thread

    const f4* P = reinterpret_cast<const f4*>(ws);
    f4 acc0 = { 0.f, 0.f, 0.f, 0.f };
    f4 acc1 = acc0;
    long base = (long)slice * rpt * 1024 + gcol;
    #pragma unroll 4
    for (int r = 0; r < rpt; r += 2) {
        acc0 += P[base + (long)r * 1024];
        acc1 += P[base + (long)(r + 1) * 1024];
    }
    part[slice][col] = acc0 + acc1;
    __syncthreads();

    #pragma unroll
    for (int stride = 32; stride >= 1; stride >>= 1) {
        if (tid < stride * 4) {
            part[slice][col] += part[slice + stride][col];
        }
        __syncthreads();
    }
    if (tid < 4) {
        reinterpret_cast<f4*>(out)[blockIdx.x * 4 + tid] = part[0][tid];
    }
}

// ------------------------------------------------------------------
// Fallback stage 1 for small ws (generic nchunk, no prefetch).
// ------------------------------------------------------------------
__global__ __launch_bounds__(256, 4) void enc_partial_small(
    const float* __restrict__ x,
    const float* __restrict__ codes,
    const float* __restrict__ scale,
    float* __restrict__ ws,
    int nchunk)
{
    __shared__ float sc_lds[2][8][SPAD];
    __shared__ float w_lds[2][8][SPAD];
    __shared__ float cn2_lds[K];

    const int tid = threadIdx.x;
    const int kg  = tid >> 4;
    const int dg  = tid & 15;
    const int d4  = dg << 2;
    const int k0  = kg << 1;

    const float4 cA0 = *reinterpret_cast<const float4*>(&codes[k0 * D + d4]);
    const float4 cA1 = *reinterpret_cast<const float4*>(&codes[k0 * D + 64 + d4]);
    const float4 cB0 = *reinterpret_cast<const float4*>(&codes[(k0 + 1) * D + d4]);
    const float4 cB1 = *reinterpret_cast<const float4*>(&codes[(k0 + 1) * D + 64 + d4]);

    {
        float pa = 0.f, pb = 0.f;
        pa = fmaf(cA0.x, cA0.x, pa); pa = fmaf(cA0.y, cA0.y, pa);
        pa = fmaf(cA0.z, cA0.z, pa); pa = fmaf(cA0.w, cA0.w, pa);
        pa = fmaf(cA1.x, cA1.x, pa); pa = fmaf(cA1.y, cA1.y, pa);
        pa = fmaf(cA1.z, cA1.z, pa); pa = fmaf(cA1.w, cA1.w, pa);
        pb = fmaf(cB0.x, cB0.x, pb); pb = fmaf(cB0.y, cB0.y, pb);
        pb = fmaf(cB0.z, cB0.z, pb); pb = fmaf(cB0.w, cB0.w, pb);
        pb = fmaf(cB1.x, cB1.x, pb); pb = fmaf(cB1.y, cB1.y, pb);
        pb = fmaf(cB1.z, cB1.z, pb); pb = fmaf(cB1.w, cB1.w, pb);
        float cn2A = sum16(pa);
        float cn2B = sum16(pb);
        if (dg == 0) {
            cn2_lds[k0]     = cn2A;
            cn2_lds[k0 + 1] = cn2B;
        }
    }
    const float sclq = scale[tid & 31];

    float4 tA0 = make_float4(0.f, 0.f, 0.f, 0.f);
    float4 tA1 = tA0, tB0 = tA0, tB1 = tA0;
    float swA = 0.f, swB = 0.f;

    const float* xb = x + (long)blockIdx.x * nchunk * 8 * D;

    for (int c = 0; c < nchunk; ++c) {
        const int p = c & 1;
        float4 xr[8][2];
        const float* xc = xb + c * 8 * D;
        #pragma unroll
        for (int n = 0; n < 8; ++n) {
            xr[n][0] = *reinterpret_cast<const float4*>(xc + n * D + d4);
            xr[n][1] = *reinterpret_cast<const float4*>(xc + n * D + 64 + d4);
        }
        #pragma unroll
        for (int n = 0; n < 8; ++n) {
            const float4 xa = xr[n][0];
            const float4 xb4 = xr[n][1];
            float nx = 0.f, dA = 0.f, dB = 0.f;
            nx = fmaf(xa.x, xa.x, nx);   nx = fmaf(xa.y, xa.y, nx);
            nx = fmaf(xa.z, xa.z, nx);   nx = fmaf(xa.w, xa.w, nx);
            nx = fmaf(xb4.x, xb4.x, nx); nx = fmaf(xb4.y, xb4.y, nx);
            nx = fmaf(xb4.z, xb4.z, nx); nx = fmaf(xb4.w, xb4.w, nx);
            dA = fmaf(xa.x, cA0.x, dA);  dA = fmaf(xa.y, cA0.y, dA);
            dA = fmaf(xa.z, cA0.z, dA);  dA = fmaf(xa.w, cA0.w, dA);
            dA = fmaf(xb4.x, cA1.x, dA); dA = fmaf(xb4.y, cA1.y, dA);
            dA = fmaf(xb4.z, cA1.z, dA); dA = fmaf(xb4.w, cA1.w, dA);
            dB = fmaf(xa.x, cB0.x, dB);  dB = fmaf(xa.y, cB0.y, dB);
            dB = fmaf(xa.z, cB0.z, dB);  dB = fmaf(xa.w, cB0.w, dB);
            dB = fmaf(xb4.x, cB1.x, dB); dB = fmaf(xb4.y, cB1.y, dB);
            dB = fmaf(xb4.z, cB1.z, dB); dB = fmaf(xb4.w, cB1.w, dB);
            float qA = fmaf(-2.f, dA, nx);
            float qB = fmaf(-2.f, dB, nx);
            qA = sum16(qA);
            qB = sum16(qB);
            if (dg == 0) {
                sc_lds[p][n][k0]     = qA;
                sc_lds[p][n][k0 + 1] = qB;
            }
        }
        __syncthreads();
        {
            const int row = tid >> 5;
            const int q   = tid & 31;
            float sq = sc_lds[p][row][q];
            float s  = sqrtf(fmaxf(sq + cn2_lds[q], 0.f)) * sclq;
            float m = max16(s);
            m = fmaxf(m, __shfl_xor(m, 16));
            float e = exp2f((s - m) * 1.44269504088896f);
            float sum = sum16(e);
            sum += __shfl_xor(sum, 16);
            w_lds[p][row][q] = e * (1.0f / sum);
        }
        __syncthreads();
        #pragma unroll
        for (int n = 0; n < 8; ++n) {
            const float2 w = *reinterpret_cast<const float2*>(&w_lds[p][n][k0]);
            const float4 xa = xr[n][0];
            const float4 xb4 = xr[n][1];
            tA0.x = fmaf(w.x, xa.x, tA0.x);
            tA0.y = fmaf(w.x, xa.y, tA0.y);
            tA0.z = fmaf(w.x, xa.z, tA0.z);
            tA0.w = fmaf(w.x, xa.w, tA0.w);
            tA1.x = fmaf(w.x, xb4.x, tA1.x);
            tA1.y = fmaf(w.x, xb4.y, tA1.y);
            tA1.z = fmaf(w.x, xb4.z, tA1.z);
            tA1.w = fmaf(w.x, xb4.w, tA1.w);
            tB0.x = fmaf(w.y, xa.x, tB0.x);
            tB0.y = fmaf(w.y, xa.y, tB0.y);
            tB0.z = fmaf(w.y, xa.z, tB0.z);
            tB0.w = fmaf(w.y, xa.w, tB0.w);
            tB1.x = fmaf(w.y, xb4.x, tB1.x);
            tB1.y = fmaf(w.y, xb4.y, tB1.y);
            tB1.z = fmaf(w.y, xb4.z, tB1.z);
            tB1.w = fmaf(w.y, xb4.w, tB1.w);
            swA += w.x;
            swB += w.y;
        }
    }

    float* o = ws + (long)blockIdx.x * (K * D) + k0 * D + d4;
    *reinterpret_cast<float4*>(o)       = make_float4(tA0.x - swA * cA0.x, tA0.y - swA * cA0.y,
                                                      tA0.z - swA * cA0.z, tA0.w - swA * cA0.w);
    *reinterpret_cast<float4*>(o + 64)  = make_float4(tA1.x - swA * cA1.x, tA1.y - swA * cA1.y,
                                                      tA1.z - swA * cA1.z, tA1.w - swA * cA1.w);
    *reinterpret_cast<float4*>(o + 128) = make_float4(tB0.x - swB * cB0.x, tB0.y - swB * cB0.y,
                                                      tB0.z - swB * cB0.z, tB0.w - swB * cB0.w);
    *reinterpret_cast<float4*>(o + 192) = make_float4(tB1.x - swB * cB1.x, tB1.y - swB * cB1.y,
                                                      tB1.z - swB * cB1.z, tB1.w - swB * cB1.w);
}

extern "C" void kernel_launch(void* const* d_in, const int* in_sizes, int n_in,
                              void* d_out, int out_size, void* d_ws, size_t ws_size,
                              hipStream_t stream) {
    const float* x     = (const float*)d_in[0];
    const float* codes = (const float*)d_in[1];
    const float* scale = (const float*)d_in[2];
    float* out = (float*)d_out;
    float* ws  = (float*)d_ws;

    if (ws_size >= (size_t)512 * K * D * sizeof(float)) {
        enc_partial<<<512, 256, 0, stream>>>(x, codes, scale, ws);
        reduce2<<<256, 256, 0, stream>>>(ws, out, 512);
    } else {
        const int grid1 = 128;                         // 2 MB ws fallback
        enc_partial_small<<<grid1, 256, 0, stream>>>(x, codes, scale, ws, N / (grid1 * 8));
        reduce2<<<256, 256, 0, stream>>>(ws, out, grid1);
    }
}

// Round 19
// 50.542 us; speedup vs baseline: 1.1858x; 1.1858x over previous
//
#include <hip/hip_runtime.h>

// Problem constants (fixed by the reference)
constexpr int N    = 16384;
constexpr int K    = 32;
constexpr int D    = 128;
constexpr int SPAD = K + 2;       // LDS score row stride (34)

typedef float f4 __attribute__((ext_vector_type(4)));

// ---- DPP helpers: butterfly reduce over 16-lane groups, pure VALU ----
template <int CTRL>
__device__ __forceinline__ float dpp_add(float v) {
    int j = __builtin_amdgcn_update_dpp(0, __float_as_int(v), CTRL, 0xF, 0xF, false);
    return v + __int_as_float(j);
}
template <int CTRL>
__device__ __forceinline__ float dpp_max(float v) {
    int j = __builtin_amdgcn_update_dpp(0, __float_as_int(v), CTRL, 0xF, 0xF, false);
    return fmaxf(v, __int_as_float(j));
}
__device__ __forceinline__ float sum16(float v) {
    v = dpp_add<0xB1>(v);
    v = dpp_add<0x4E>(v);
    v = dpp_add<0x141>(v);
    v = dpp_add<0x140>(v);
    return v;
}
__device__ __forceinline__ float max16(float v) {
    v = dpp_max<0xB1>(v);
    v = dpp_max<0x4E>(v);
    v = dpp_max<0x141>(v);
    v = dpp_max<0x140>(v);
    return v;
}

// ---- Pipeline phases as MACROS (no lambdas: R18's [&] closures failed
// SROA and generated ~1 KB/thread of scratch traffic; macros guarantee
// pure inline codegen). P must be a literal 0 or 1. ----
#define PHASE1(P)                                                            \
    do {                                                                     \
        _Pragma("unroll")                                                    \
        for (int n = 0; n < 8; ++n) {                                        \
            const float4 xa  = *reinterpret_cast<const float4*>(&xs[P][n][d4]);      \
            const float4 xb4 = *reinterpret_cast<const float4*>(&xs[P][n][64 + d4]); \
            float nx = 0.f, dA = 0.f, dB = 0.f, r_;                          \
            nx = fmaf(xa.x, xa.x, nx);   nx = fmaf(xa.y, xa.y, nx);          \
            nx = fmaf(xa.z, xa.z, nx);   nx = fmaf(xa.w, xa.w, nx);          \
            nx = fmaf(xb4.x, xb4.x, nx); nx = fmaf(xb4.y, xb4.y, nx);        \
            nx = fmaf(xb4.z, xb4.z, nx); nx = fmaf(xb4.w, xb4.w, nx);        \
            dA = fmaf(xa.x, cA0.x, dA);  dA = fmaf(xa.y, cA0.y, dA);         \
            dA = fmaf(xa.z, cA0.z, dA);  dA = fmaf(xa.w, cA0.w, dA);         \
            dA = fmaf(xb4.x, cA1.x, dA); dA = fmaf(xb4.y, cA1.y, dA);        \
            dA = fmaf(xb4.z, cA1.z, dA); dA = fmaf(xb4.w, cA1.w, dA);        \
            dB = fmaf(xa.x, cB0.x, dB);  dB = fmaf(xa.y, cB0.y, dB);         \
            dB = fmaf(xa.z, cB0.z, dB);  dB = fmaf(xa.w, cB0.w, dB);         \
            dB = fmaf(xb4.x, cB1.x, dB); dB = fmaf(xb4.y, cB1.y, dB);        \
            dB = fmaf(xb4.z, cB1.z, dB); dB = fmaf(xb4.w, cB1.w, dB);        \
            float qA = fmaf(-2.f, dA, nx);                                   \
            float qB = fmaf(-2.f, dB, nx);                                   \
            qA = sum16(qA);                                                  \
            qB = sum16(qB);                                                  \
            if (dg == 0) {                                                   \
                sc_lds[P][n][k0]     = qA;                                   \
                sc_lds[P][n][k0 + 1] = qB;                                   \
            }                                                                \
            (void)r_;                                                        \
        }                                                                    \
    } while (0)

#define SOFTMAX(P)                                                           \
    do {                                                                     \
        const int row_ = tid >> 5;                                           \
        const int q_   = tid & 31;                                           \
        float sq_ = sc_lds[P][row_][q_];                                     \
        float s_  = sqrtf(fmaxf(sq_ + cn2_lds[q_], 0.f)) * sclq;             \
        float m_ = max16(s_);                                                \
        m_ = fmaxf(m_, __shfl_xor(m_, 16));                                  \
        float e_ = exp2f((s_ - m_) * 1.44269504088896f);                     \
        float su_ = sum16(e_);                                               \
        su_ += __shfl_xor(su_, 16);                                          \
        w_lds[P][row_][q_] = e_ * (1.0f / su_);                              \
    } while (0)

#define PHASE2(P)                                                            \
    do {                                                                     \
        _Pragma("unroll")                                                    \
        for (int n = 0; n < 8; ++n) {                                        \
            const float2 w = *reinterpret_cast<const float2*>(&w_lds[P][n][k0]);     \
            const float4 xa  = *reinterpret_cast<const float4*>(&xs[P][n][d4]);      \
            const float4 xb4 = *reinterpret_cast<const float4*>(&xs[P][n][64 + d4]); \
            tA0.x = fmaf(w.x, xa.x, tA0.x);                                  \
            tA0.y = fmaf(w.x, xa.y, tA0.y);                                  \
            tA0.z = fmaf(w.x, xa.z, tA0.z);                                  \
            tA0.w = fmaf(w.x, xa.w, tA0.w);                                  \
            tA1.x = fmaf(w.x, xb4.x, tA1.x);                                 \
            tA1.y = fmaf(w.x, xb4.y, tA1.y);                                 \
            tA1.z = fmaf(w.x, xb4.z, tA1.z);                                 \
            tA1.w = fmaf(w.x, xb4.w, tA1.w);                                 \
            tB0.x = fmaf(w.y, xa.x, tB0.x);                                  \
            tB0.y = fmaf(w.y, xa.y, tB0.y);                                  \
            tB0.z = fmaf(w.y, xa.z, tB0.z);                                  \
            tB0.w = fmaf(w.y, xa.w, tB0.w);                                  \
            tB1.x = fmaf(w.y, xb4.x, tB1.x);                                 \
            tB1.y = fmaf(w.y, xb4.y, tB1.y);                                 \
            tB1.z = fmaf(w.y, xb4.z, tB1.z);                                 \
            tB1.w = fmaf(w.y, xb4.w, tB1.w);                                 \
            swA += w.x;                                                      \
            swB += w.y;                                                      \
        }                                                                    \
    } while (0)

// ------------------------------------------------------------------
// Stage 1: cooperative async-prefetch pipeline (macro form).
// grid=512, 32 rows/block, 4 chunks of 8 rows. x chunk (4 KB) staged
// into double-buffered LDS; each thread prefetches ONE float4 of the
// next chunk while computing the current one.
// ------------------------------------------------------------------
__global__ __launch_bounds__(256, 4) void enc_partial(
    const float* __restrict__ x,      // (N, D)
    const float* __restrict__ codes,  // (K, D)
    const float* __restrict__ scale,  // (K,)
    float* __restrict__ ws)           // (512, K*D)
{
    __shared__ float xs[2][8][D];          // 8 KB x tile, double-buffered
    __shared__ float sc_lds[2][8][SPAD];
    __shared__ float w_lds[2][8][SPAD];
    __shared__ float cn2_lds[K];

    const int tid = threadIdx.x;
    const int kg  = tid >> 4;
    const int dg  = tid & 15;
    const int d4  = dg << 2;
    const int k0  = kg << 1;
    (void)kg;

    const float4* xg4 = reinterpret_cast<const float4*>(x + (long)blockIdx.x * 32 * D);
    float4* xs40 = reinterpret_cast<float4*>(&xs[0][0][0]);
    float4* xs41 = reinterpret_cast<float4*>(&xs[1][0][0]);

    // ---- prologue: issue chunk-0 load, hide some latency under cn2 ----
    float4 pf = xg4[tid];

    const float4 cA0 = *reinterpret_cast<const float4*>(&codes[k0 * D + d4]);
    const float4 cA1 = *reinterpret_cast<const float4*>(&codes[k0 * D + 64 + d4]);
    const float4 cB0 = *reinterpret_cast<const float4*>(&codes[(k0 + 1) * D + d4]);
    const float4 cB1 = *reinterpret_cast<const float4*>(&codes[(k0 + 1) * D + 64 + d4]);
    {
        float pa = 0.f, pb = 0.f;
        pa = fmaf(cA0.x, cA0.x, pa); pa = fmaf(cA0.y, cA0.y, pa);
        pa = fmaf(cA0.z, cA0.z, pa); pa = fmaf(cA0.w, cA0.w, pa);
        pa = fmaf(cA1.x, cA1.x, pa); pa = fmaf(cA1.y, cA1.y, pa);
        pa = fmaf(cA1.z, cA1.z, pa); pa = fmaf(cA1.w, cA1.w, pa);
        pb = fmaf(cB0.x, cB0.x, pb); pb = fmaf(cB0.y, cB0.y, pb);
        pb = fmaf(cB0.z, cB0.z, pb); pb = fmaf(cB0.w, cB0.w, pb);
        pb = fmaf(cB1.x, cB1.x, pb); pb = fmaf(cB1.y, cB1.y, pb);
        pb = fmaf(cB1.z, cB1.z, pb); pb = fmaf(cB1.w, cB1.w, pb);
        float cn2A = sum16(pa);
        float cn2B = sum16(pb);
        if (dg == 0) {
            cn2_lds[k0]     = cn2A;
            cn2_lds[k0 + 1] = cn2B;
        }
    }
    const float sclq = scale[tid & 31];

    xs40[tid] = pf;              // chunk 0 -> xs[0]
    pf = xg4[256 + tid];         // issue chunk 1
    __syncthreads();             // xs[0] + cn2 ready

    float4 tA0 = make_float4(0.f, 0.f, 0.f, 0.f);
    float4 tA1 = tA0, tB0 = tA0, tB1 = tA0;
    float swA = 0.f, swB = 0.f;

    // ---- chunk 0 (p=0); pf holds chunk 1 ----
    PHASE1(0);
    __syncthreads();
    xs41[tid] = pf;              // chunk 1 -> xs[1]
    SOFTMAX(0);
    pf = xg4[512 + tid];         // issue chunk 2
    __syncthreads();
    PHASE2(0);

    // ---- chunk 1 (p=1); pf holds chunk 2 ----
    PHASE1(1);
    __syncthreads();
    xs40[tid] = pf;              // chunk 2 -> xs[0]
    SOFTMAX(1);
    pf = xg4[768 + tid];         // issue chunk 3
    __syncthreads();
    PHASE2(1);

    // ---- chunk 2 (p=0); pf holds chunk 3 ----
    PHASE1(0);
    __syncthreads();
    xs41[tid] = pf;              // chunk 3 -> xs[1]
    SOFTMAX(0);
    __syncthreads();
    PHASE2(0);

    // ---- chunk 3 (p=1) ----
    PHASE1(1);
    __syncthreads();
    SOFTMAX(1);
    __syncthreads();
    PHASE2(1);

    // ---- Epilogue: plain cached stores (keep ws in L2/L3) ----
    float* o = ws + (long)blockIdx.x * (K * D) + k0 * D + d4;
    *reinterpret_cast<float4*>(o)       = make_float4(tA0.x - swA * cA0.x, tA0.y - swA * cA0.y,
                                                      tA0.z - swA * cA0.z, tA0.w - swA * cA0.w);
    *reinterpret_cast<float4*>(o + 64)  = make_float4(tA1.x - swA * cA1.x, tA1.y - swA * cA1.y,
                                                      tA1.z - swA * cA1.z, tA1.w - swA * cA1.w);
    *reinterpret_cast<float4*>(o + 128) = make_float4(tB0.x - swB * cB0.x, tB0.y - swB * cB0.y,
                                                      tB0.z - swB * cB0.z, tB0.w - swB * cB0.w);
    *reinterpret_cast<float4*>(o + 192) = make_float4(tB1.x - swB * cB1.x, tB1.y - swB * cB1.y,
                                                      tB1.z - swB * cB1.z, tB1.w - swB * cB1.w);
}

// ------------------------------------------------------------------
// Stage 2: identical to round 14 (plain cached loads, unroll ILP).
// ------------------------------------------------------------------
__global__ __launch_bounds__(256) void reduce2(
    const float* __restrict__ ws, float* __restrict__ out, int nrows)
{
    __shared__ f4 part[64][4];

    const int tid   = threadIdx.x;
    const int col   = tid & 3;
    const int slice = tid >> 2;                  // 0..63
    const int gcol  = blockIdx.x * 4 + col;      // 0..1023
    const int rpt   = nrows >> 6;                // rows per thread

    const f4* P = reinterpret_cast<const f4*>(ws);
    f4 acc0 = { 0.f, 0.f, 0.f, 0.f };
    f4 acc1 = acc0;
    long base = (long)slice * rpt * 1024 + gcol;
    #pragma unroll 4
    for (int r = 0; r < rpt; r += 2) {
        acc0 += P[base + (long)r * 1024];
        acc1 += P[base + (long)(r + 1) * 1024];
    }
    part[slice][col] = acc0 + acc1;
    __syncthreads();

    #pragma unroll
    for (int stride = 32; stride >= 1; stride >>= 1) {
        if (tid < stride * 4) {
            part[slice][col] += part[slice + stride][col];
        }
        __syncthreads();
    }
    if (tid < 4) {
        reinterpret_cast<f4*>(out)[blockIdx.x * 4 + tid] = part[0][tid];
    }
}

// ------------------------------------------------------------------
// Fallback stage 1 for small ws (generic nchunk, no prefetch).
// ------------------------------------------------------------------
__global__ __launch_bounds__(256, 4) void enc_partial_small(
    const float* __restrict__ x,
    const float* __restrict__ codes,
    const float* __restrict__ scale,
    float* __restrict__ ws,
    int nchunk)
{
    __shared__ float sc_lds[2][8][SPAD];
    __shared__ float w_lds[2][8][SPAD];
    __shared__ float cn2_lds[K];

    const int tid = threadIdx.x;
    const int kg  = tid >> 4;
    const int dg  = tid & 15;
    const int d4  = dg << 2;
    const int k0  = kg << 1;
    (void)kg;

    const float4 cA0 = *reinterpret_cast<const float4*>(&codes[k0 * D + d4]);
    const float4 cA1 = *reinterpret_cast<const float4*>(&codes[k0 * D + 64 + d4]);
    const float4 cB0 = *reinterpret_cast<const float4*>(&codes[(k0 + 1) * D + d4]);
    const float4 cB1 = *reinterpret_cast<const float4*>(&codes[(k0 + 1) * D + 64 + d4]);

    {
        float pa = 0.f, pb = 0.f;
        pa = fmaf(cA0.x, cA0.x, pa); pa = fmaf(cA0.y, cA0.y, pa);
        pa = fmaf(cA0.z, cA0.z, pa); pa = fmaf(cA0.w, cA0.w, pa);
        pa = fmaf(cA1.x, cA1.x, pa); pa = fmaf(cA1.y, cA1.y, pa);
        pa = fmaf(cA1.z, cA1.z, pa); pa = fmaf(cA1.w, cA1.w, pa);
        pb = fmaf(cB0.x, cB0.x, pb); pb = fmaf(cB0.y, cB0.y, pb);
        pb = fmaf(cB0.z, cB0.z, pb); pb = fmaf(cB0.w, cB0.w, pb);
        pb = fmaf(cB1.x, cB1.x, pb); pb = fmaf(cB1.y, cB1.y, pb);
        pb = fmaf(cB1.z, cB1.z, pb); pb = fmaf(cB1.w, cB1.w, pb);
        float cn2A = sum16(pa);
        float cn2B = sum16(pb);
        if (dg == 0) {
            cn2_lds[k0]     = cn2A;
            cn2_lds[k0 + 1] = cn2B;
        }
    }
    const float sclq = scale[tid & 31];

    float4 tA0 = make_float4(0.f, 0.f, 0.f, 0.f);
    float4 tA1 = tA0, tB0 = tA0, tB1 = tA0;
    float swA = 0.f, swB = 0.f;

    const float* xb = x + (long)blockIdx.x * nchunk * 8 * D;

    for (int c = 0; c < nchunk; ++c) {
        const int p = c & 1;
        float4 xr[8][2];
        const float* xc = xb + c * 8 * D;
        #pragma unroll
        for (int n = 0; n < 8; ++n) {
            xr[n][0] = *reinterpret_cast<const float4*>(xc + n * D + d4);
            xr[n][1] = *reinterpret_cast<const float4*>(xc + n * D + 64 + d4);
        }
        #pragma unroll
        for (int n = 0; n < 8; ++n) {
            const float4 xa = xr[n][0];
            const float4 xb4 = xr[n][1];
            float nx = 0.f, dA = 0.f, dB = 0.f;
            nx = fmaf(xa.x, xa.x, nx);   nx = fmaf(xa.y, xa.y, nx);
            nx = fmaf(xa.z, xa.z, nx);   nx = fmaf(xa.w, xa.w, nx);
            nx = fmaf(xb4.x, xb4.x, nx); nx = fmaf(xb4.y, xb4.y, nx);
            nx = fmaf(xb4.z, xb4.z, nx); nx = fmaf(xb4.w, xb4.w, nx);
            dA = fmaf(xa.x, cA0.x, dA);  dA = fmaf(xa.y, cA0.y, dA);
            dA = fmaf(xa.z, cA0.z, dA);  dA = fmaf(xa.w, cA0.w, dA);
            dA = fmaf(xb4.x, cA1.x, dA); dA = fmaf(xb4.y, cA1.y, dA);
            dA = fmaf(xb4.z, cA1.z, dA); dA = fmaf(xb4.w, cA1.w, dA);
            dB = fmaf(xa.x, cB0.x, dB);  dB = fmaf(xa.y, cB0.y, dB);
            dB = fmaf(xa.z, cB0.z, dB);  dB = fmaf(xa.w, cB0.w, dB);
            dB = fmaf(xb4.x, cB1.x, dB); dB = fmaf(xb4.y, cB1.y, dB);
            dB = fmaf(xb4.z, cB1.z, dB); dB = fmaf(xb4.w, cB1.w, dB);
            float qA = fmaf(-2.f, dA, nx);
            float qB = fmaf(-2.f, dB, nx);
            qA = sum16(qA);
            qB = sum16(qB);
            if (dg == 0) {
                sc_lds[p][n][k0]     = qA;
                sc_lds[p][n][k0 + 1] = qB;
            }
        }
        __syncthreads();
        {
            const int row = tid >> 5;
            const int q   = tid & 31;
            float sq = sc_lds[p][row][q];
            float s  = sqrtf(fmaxf(sq + cn2_lds[q], 0.f)) * sclq;
            float m = max16(s);
            m = fmaxf(m, __shfl_xor(m, 16));
            float e = exp2f((s - m) * 1.44269504088896f);
            float sum = sum16(e);
            sum += __shfl_xor(sum, 16);
            w_lds[p][row][q] = e * (1.0f / sum);
        }
        __syncthreads();
        #pragma unroll
        for (int n = 0; n < 8; ++n) {
            const float2 w = *reinterpret_cast<const float2*>(&w_lds[p][n][k0]);
            const float4 xa = xr[n][0];
            const float4 xb4 = xr[n][1];
            tA0.x = fmaf(w.x, xa.x, tA0.x);
            tA0.y = fmaf(w.x, xa.y, tA0.y);
            tA0.z = fmaf(w.x, xa.z, tA0.z);
            tA0.w = fmaf(w.x, xa.w, tA0.w);
            tA1.x = fmaf(w.x, xb4.x, tA1.x);
            tA1.y = fmaf(w.x, xb4.y, tA1.y);
            tA1.z = fmaf(w.x, xb4.z, tA1.z);
            tA1.w = fmaf(w.x, xb4.w, tA1.w);
            tB0.x = fmaf(w.y, xa.x, tB0.x);
            tB0.y = fmaf(w.y, xa.y, tB0.y);
            tB0.z = fmaf(w.y, xa.z, tB0.z);
            tB0.w = fmaf(w.y, xa.w, tB0.w);
            tB1.x = fmaf(w.y, xb4.x, tB1.x);
            tB1.y = fmaf(w.y, xb4.y, tB1.y);
            tB1.z = fmaf(w.y, xb4.z, tB1.z);
            tB1.w = fmaf(w.y, xb4.w, tB1.w);
            swA += w.x;
            swB += w.y;
        }
    }

    float* o = ws + (long)blockIdx.x * (K * D) + k0 * D + d4;
    *reinterpret_cast<float4*>(o)       = make_float4(tA0.x - swA * cA0.x, tA0.y - swA * cA0.y,
                                                      tA0.z - swA * cA0.z, tA0.w - swA * cA0.w);
    *reinterpret_cast<float4*>(o + 64)  = make_float4(tA1.x - swA * cA1.x, tA1.y - swA * cA1.y,
                                                      tA1.z - swA * cA1.z, tA1.w - swA * cA1.w);
    *reinterpret_cast<float4*>(o + 128) = make_float4(tB0.x - swB * cB0.x, tB0.y - swB * cB0.y,
                                                      tB0.z - swB * cB0.z, tB0.w - swB * cB0.w);
    *reinterpret_cast<float4*>(o + 192) = make_float4(tB1.x - swB * cB1.x, tB1.y - swB * cB1.y,
                                                      tB1.z - swB * cB1.z, tB1.w - swB * cB1.w);
}

extern "C" void kernel_launch(void* const* d_in, const int* in_sizes, int n_in,
                              void* d_out, int out_size, void* d_ws, size_t ws_size,
                              hipStream_t stream) {
    const float* x     = (const float*)d_in[0];
    const float* codes = (const float*)d_in[1];
    const float* scale = (const float*)d_in[2];
    float* out = (float*)d_out;
    float* ws  = (float*)d_ws;

    if (ws_size >= (size_t)512 * K * D * sizeof(float)) {
        enc_partial<<<512, 256, 0, stream>>>(x, codes, scale, ws);
        reduce2<<<256, 256, 0, stream>>>(ws, out, 512);
    } else {
        const int grid1 = 128;                         // 2 MB ws fallback
        enc_partial_small<<<grid1, 256, 0, stream>>>(x, codes, scale, ws, N / (grid1 * 8));
        reduce2<<<256, 256, 0, stream>>>(ws, out, grid1);
    }
}

// Round 20
// 25.003 us; speedup vs baseline: 2.3970x; 2.0215x over previous
//
#include <hip/hip_runtime.h>

// Problem constants (fixed by the reference)
constexpr int N    = 16384;
constexpr int K    = 32;
constexpr int D    = 128;
constexpr int SPAD = K + 2;       // LDS score row stride (34)

typedef float f4 __attribute__((ext_vector_type(4)));

// ---- DPP helpers: butterfly reduce over 16-lane groups, pure VALU ----
template <int CTRL>
__device__ __forceinline__ float dpp_add(float v) {
    int j = __builtin_amdgcn_update_dpp(0, __float_as_int(v), CTRL, 0xF, 0xF, false);
    return v + __int_as_float(j);
}
template <int CTRL>
__device__ __forceinline__ float dpp_max(float v) {
    int j = __builtin_amdgcn_update_dpp(0, __float_as_int(v), CTRL, 0xF, 0xF, false);
    return fmaxf(v, __int_as_float(j));
}
__device__ __forceinline__ float sum16(float v) {
    v = dpp_add<0xB1>(v);
    v = dpp_add<0x4E>(v);
    v = dpp_add<0x141>(v);
    v = dpp_add<0x140>(v);
    return v;
}
__device__ __forceinline__ float max16(float v) {
    v = dpp_max<0xB1>(v);
    v = dpp_max<0x4E>(v);
    v = dpp_max<0x141>(v);
    v = dpp_max<0x140>(v);
    return v;
}

// ---- Pipeline phases as MACROS (pure inline codegen; P literal 0/1) ----
#define PHASE1(P)                                                            \
    do {                                                                     \
        _Pragma("unroll")                                                    \
        for (int n = 0; n < 8; ++n) {                                        \
            const float4 xa  = *reinterpret_cast<const float4*>(&xs[P][n][d4]);      \
            const float4 xb4 = *reinterpret_cast<const float4*>(&xs[P][n][64 + d4]); \
            float nx = 0.f, dA = 0.f, dB = 0.f;                              \
            nx = fmaf(xa.x, xa.x, nx);   nx = fmaf(xa.y, xa.y, nx);          \
            nx = fmaf(xa.z, xa.z, nx);   nx = fmaf(xa.w, xa.w, nx);          \
            nx = fmaf(xb4.x, xb4.x, nx); nx = fmaf(xb4.y, xb4.y, nx);        \
            nx = fmaf(xb4.z, xb4.z, nx); nx = fmaf(xb4.w, xb4.w, nx);        \
            dA = fmaf(xa.x, cA0.x, dA);  dA = fmaf(xa.y, cA0.y, dA);         \
            dA = fmaf(xa.z, cA0.z, dA);  dA = fmaf(xa.w, cA0.w, dA);         \
            dA = fmaf(xb4.x, cA1.x, dA); dA = fmaf(xb4.y, cA1.y, dA);        \
            dA = fmaf(xb4.z, cA1.z, dA); dA = fmaf(xb4.w, cA1.w, dA);        \
            dB = fmaf(xa.x, cB0.x, dB);  dB = fmaf(xa.y, cB0.y, dB);         \
            dB = fmaf(xa.z, cB0.z, dB);  dB = fmaf(xa.w, cB0.w, dB);         \
            dB = fmaf(xb4.x, cB1.x, dB); dB = fmaf(xb4.y, cB1.y, dB);        \
            dB = fmaf(xb4.z, cB1.z, dB); dB = fmaf(xb4.w, cB1.w, dB);        \
            float qA = fmaf(-2.f, dA, nx);                                   \
            float qB = fmaf(-2.f, dB, nx);                                   \
            qA = sum16(qA);                                                  \
            qB = sum16(qB);                                                  \
            if (dg == 0) {                                                   \
                sc_lds[P][n][k0]     = qA;                                   \
                sc_lds[P][n][k0 + 1] = qB;                                   \
            }                                                                \
        }                                                                    \
    } while (0)

#define SOFTMAX(P)                                                           \
    do {                                                                     \
        const int row_ = tid >> 5;                                           \
        const int q_   = tid & 31;                                           \
        float sq_ = sc_lds[P][row_][q_];                                     \
        float s_  = sqrtf(fmaxf(sq_ + cn2_lds[q_], 0.f)) * sclq;             \
        float m_ = max16(s_);                                                \
        m_ = fmaxf(m_, __shfl_xor(m_, 16));                                  \
        float e_ = exp2f((s_ - m_) * 1.44269504088896f);                     \
        float su_ = sum16(e_);                                               \
        su_ += __shfl_xor(su_, 16);                                          \
        w_lds[P][row_][q_] = e_ * (1.0f / su_);                              \
    } while (0)

#define PHASE2(P)                                                            \
    do {                                                                     \
        _Pragma("unroll")                                                    \
        for (int n = 0; n < 8; ++n) {                                        \
            const float2 w = *reinterpret_cast<const float2*>(&w_lds[P][n][k0]);     \
            const float4 xa  = *reinterpret_cast<const float4*>(&xs[P][n][d4]);      \
            const float4 xb4 = *reinterpret_cast<const float4*>(&xs[P][n][64 + d4]); \
            tA0.x = fmaf(w.x, xa.x, tA0.x);                                  \
            tA0.y = fmaf(w.x, xa.y, tA0.y);                                  \
            tA0.z = fmaf(w.x, xa.z, tA0.z);                                  \
            tA0.w = fmaf(w.x, xa.w, tA0.w);                                  \
            tA1.x = fmaf(w.x, xb4.x, tA1.x);                                 \
            tA1.y = fmaf(w.x, xb4.y, tA1.y);                                 \
            tA1.z = fmaf(w.x, xb4.z, tA1.z);                                 \
            tA1.w = fmaf(w.x, xb4.w, tA1.w);                                 \
            tB0.x = fmaf(w.y, xa.x, tB0.x);                                  \
            tB0.y = fmaf(w.y, xa.y, tB0.y);                                  \
            tB0.z = fmaf(w.y, xa.z, tB0.z);                                  \
            tB0.w = fmaf(w.y, xa.w, tB0.w);                                  \
            tB1.x = fmaf(w.y, xb4.x, tB1.x);                                 \
            tB1.y = fmaf(w.y, xb4.y, tB1.y);                                 \
            tB1.z = fmaf(w.y, xb4.z, tB1.z);                                 \
            tB1.w = fmaf(w.y, xb4.w, tB1.w);                                 \
            swA += w.x;                                                      \
            swB += w.y;                                                      \
        }                                                                    \
    } while (0)

// ------------------------------------------------------------------
// Stage 1: cooperative async-prefetch pipeline.
// __launch_bounds__(256,2): VGPR cap 128 — R18/R19's (256,4) capped
// the allocator at 64 VGPRs (observed) and forced ~1 KB/thread of
// scratch spill (FETCH 61 MB / WRITE 122 MB). Grid is 512 blocks =
// 2 blocks/CU regardless, so occupancy is unchanged.
// ------------------------------------------------------------------
__global__ __launch_bounds__(256, 2) void enc_partial(
    const float* __restrict__ x,      // (N, D)
    const float* __restrict__ codes,  // (K, D)
    const float* __restrict__ scale,  // (K,)
    float* __restrict__ ws)           // (512, K*D)
{
    __shared__ float xs[2][8][D];          // 8 KB x tile, double-buffered
    __shared__ float sc_lds[2][8][SPAD];
    __shared__ float w_lds[2][8][SPAD];
    __shared__ float cn2_lds[K];

    const int tid = threadIdx.x;
    const int dg  = tid & 15;
    const int d4  = dg << 2;
    const int k0  = (tid >> 4) << 1;

    const float4* xg4 = reinterpret_cast<const float4*>(x + (long)blockIdx.x * 32 * D);
    float4* xs40 = reinterpret_cast<float4*>(&xs[0][0][0]);
    float4* xs41 = reinterpret_cast<float4*>(&xs[1][0][0]);

    // ---- prologue: issue chunk-0 load, hide some latency under cn2 ----
    float4 pf = xg4[tid];

    const float4 cA0 = *reinterpret_cast<const float4*>(&codes[k0 * D + d4]);
    const float4 cA1 = *reinterpret_cast<const float4*>(&codes[k0 * D + 64 + d4]);
    const float4 cB0 = *reinterpret_cast<const float4*>(&codes[(k0 + 1) * D + d4]);
    const float4 cB1 = *reinterpret_cast<const float4*>(&codes[(k0 + 1) * D + 64 + d4]);
    {
        float pa = 0.f, pb = 0.f;
        pa = fmaf(cA0.x, cA0.x, pa); pa = fmaf(cA0.y, cA0.y, pa);
        pa = fmaf(cA0.z, cA0.z, pa); pa = fmaf(cA0.w, cA0.w, pa);
        pa = fmaf(cA1.x, cA1.x, pa); pa = fmaf(cA1.y, cA1.y, pa);
        pa = fmaf(cA1.z, cA1.z, pa); pa = fmaf(cA1.w, cA1.w, pa);
        pb = fmaf(cB0.x, cB0.x, pb); pb = fmaf(cB0.y, cB0.y, pb);
        pb = fmaf(cB0.z, cB0.z, pb); pb = fmaf(cB0.w, cB0.w, pb);
        pb = fmaf(cB1.x, cB1.x, pb); pb = fmaf(cB1.y, cB1.y, pb);
        pb = fmaf(cB1.z, cB1.z, pb); pb = fmaf(cB1.w, cB1.w, pb);
        float cn2A = sum16(pa);
        float cn2B = sum16(pb);
        if (dg == 0) {
            cn2_lds[k0]     = cn2A;
            cn2_lds[k0 + 1] = cn2B;
        }
    }
    const float sclq = scale[tid & 31];

    xs40[tid] = pf;              // chunk 0 -> xs[0]
    pf = xg4[256 + tid];         // issue chunk 1
    __syncthreads();             // xs[0] + cn2 ready

    float4 tA0 = make_float4(0.f, 0.f, 0.f, 0.f);
    float4 tA1 = tA0, tB0 = tA0, tB1 = tA0;
    float swA = 0.f, swB = 0.f;

    // ---- chunk 0 (p=0); pf holds chunk 1 ----
    PHASE1(0);
    __syncthreads();
    xs41[tid] = pf;              // chunk 1 -> xs[1]
    SOFTMAX(0);
    pf = xg4[512 + tid];         // issue chunk 2
    __syncthreads();
    PHASE2(0);

    // ---- chunk 1 (p=1); pf holds chunk 2 ----
    PHASE1(1);
    __syncthreads();
    xs40[tid] = pf;              // chunk 2 -> xs[0]
    SOFTMAX(1);
    pf = xg4[768 + tid];         // issue chunk 3
    __syncthreads();
    PHASE2(1);

    // ---- chunk 2 (p=0); pf holds chunk 3 ----
    PHASE1(0);
    __syncthreads();
    xs41[tid] = pf;              // chunk 3 -> xs[1]
    SOFTMAX(0);
    __syncthreads();
    PHASE2(0);

    // ---- chunk 3 (p=1) ----
    PHASE1(1);
    __syncthreads();
    SOFTMAX(1);
    __syncthreads();
    PHASE2(1);

    // ---- Epilogue: plain cached stores (keep ws in L2/L3) ----
    float* o = ws + (long)blockIdx.x * (K * D) + k0 * D + d4;
    *reinterpret_cast<float4*>(o)       = make_float4(tA0.x - swA * cA0.x, tA0.y - swA * cA0.y,
                                                      tA0.z - swA * cA0.z, tA0.w - swA * cA0.w);
    *reinterpret_cast<float4*>(o + 64)  = make_float4(tA1.x - swA * cA1.x, tA1.y - swA * cA1.y,
                                                      tA1.z - swA * cA1.z, tA1.w - swA * cA1.w);
    *reinterpret_cast<float4*>(o + 128) = make_float4(tB0.x - swB * cB0.x, tB0.y - swB * cB0.y,
                                                      tB0.z - swB * cB0.z, tB0.w - swB * cB0.w);
    *reinterpret_cast<float4*>(o + 192) = make_float4(tB1.x - swB * cB1.x, tB1.y - swB * cB1.y,
                                                      tB1.z - swB * cB1.z, tB1.w - swB * cB1.w);
}

// ------------------------------------------------------------------
// Stage 2: identical to round 14 (plain cached loads, unroll ILP).
// ------------------------------------------------------------------
__global__ __launch_bounds__(256) void reduce2(
    const float* __restrict__ ws, float* __restrict__ out, int nrows)
{
    __shared__ f4 part[64][4];

    const int tid   = threadIdx.x;
    const int col   = tid & 3;
    const int slice = tid >> 2;                  // 0..63
    const int gcol  = blockIdx.x * 4 + col;      // 0..1023
    const int rpt   = nrows >> 6;                // rows per thread

    const f4* P = reinterpret_cast<const f4*>(ws);
    f4 acc0 = { 0.f, 0.f, 0.f, 0.f };
    f4 acc1 = acc0;
    long base = (long)slice * rpt * 1024 + gcol;
    #pragma unroll 4
    for (int r = 0; r < rpt; r += 2) {
        acc0 += P[base + (long)r * 1024];
        acc1 += P[base + (long)(r + 1) * 1024];
    }
    part[slice][col] = acc0 + acc1;
    __syncthreads();

    #pragma unroll
    for (int stride = 32; stride >= 1; stride >>= 1) {
        if (tid < stride * 4) {
            part[slice][col] += part[slice + stride][col];
        }
        __syncthreads();
    }
    if (tid < 4) {
        reinterpret_cast<f4*>(out)[blockIdx.x * 4 + tid] = part[0][tid];
    }
}

// ------------------------------------------------------------------
// Fallback stage 1 for small ws (generic nchunk, no prefetch).
// Also (256,2): its xr[8][2] buffer alone needs 64 VGPRs.
// ------------------------------------------------------------------
__global__ __launch_bounds__(256, 2) void enc_partial_small(
    const float* __restrict__ x,
    const float* __restrict__ codes,
    const float* __restrict__ scale,
    float* __restrict__ ws,
    int nchunk)
{
    __shared__ float sc_lds[2][8][SPAD];
    __shared__ float w_lds[2][8][SPAD];
    __shared__ float cn2_lds[K];

    const int tid = threadIdx.x;
    const int dg  = tid & 15;
    const int d4  = dg << 2;
    const int k0  = (tid >> 4) << 1;

    const float4 cA0 = *reinterpret_cast<const float4*>(&codes[k0 * D + d4]);
    const float4 cA1 = *reinterpret_cast<const float4*>(&codes[k0 * D + 64 + d4]);
    const float4 cB0 = *reinterpret_cast<const float4*>(&codes[(k0 + 1) * D + d4]);
    const float4 cB1 = *reinterpret_cast<const float4*>(&codes[(k0 + 1) * D + 64 + d4]);

    {
        float pa = 0.f, pb = 0.f;
        pa = fmaf(cA0.x, cA0.x, pa); pa = fmaf(cA0.y, cA0.y, pa);
        pa = fmaf(cA0.z, cA0.z, pa); pa = fmaf(cA0.w, cA0.w, pa);
        pa = fmaf(cA1.x, cA1.x, pa); pa = fmaf(cA1.y, cA1.y, pa);
        pa = fmaf(cA1.z, cA1.z, pa); pa = fmaf(cA1.w, cA1.w, pa);
        pb = fmaf(cB0.x, cB0.x, pb); pb = fmaf(cB0.y, cB0.y, pb);
        pb = fmaf(cB0.z, cB0.z, pb); pb = fmaf(cB0.w, cB0.w, pb);
        pb = fmaf(cB1.x, cB1.x, pb); pb = fmaf(cB1.y, cB1.y, pb);
        pb = fmaf(cB1.z, cB1.z, pb); pb = fmaf(cB1.w, cB1.w, pb);
        float cn2A = sum16(pa);
        float cn2B = sum16(pb);
        if (dg == 0) {
            cn2_lds[k0]     = cn2A;
            cn2_lds[k0 + 1] = cn2B;
        }
    }
    const float sclq = scale[tid & 31];

    float4 tA0 = make_float4(0.f, 0.f, 0.f, 0.f);
    float4 tA1 = tA0, tB0 = tA0, tB1 = tA0;
    float swA = 0.f, swB = 0.f;

    const float* xb = x + (long)blockIdx.x * nchunk * 8 * D;

    for (int c = 0; c < nchunk; ++c) {
        const int p = c & 1;
        float4 xr[8][2];
        const float* xc = xb + c * 8 * D;
        #pragma unroll
        for (int n = 0; n < 8; ++n) {
            xr[n][0] = *reinterpret_cast<const float4*>(xc + n * D + d4);
            xr[n][1] = *reinterpret_cast<const float4*>(xc + n * D + 64 + d4);
        }
        #pragma unroll
        for (int n = 0; n < 8; ++n) {
            const float4 xa = xr[n][0];
            const float4 xb4 = xr[n][1];
            float nx = 0.f, dA = 0.f, dB = 0.f;
            nx = fmaf(xa.x, xa.x, nx);   nx = fmaf(xa.y, xa.y, nx);
            nx = fmaf(xa.z, xa.z, nx);   nx = fmaf(xa.w, xa.w, nx);
            nx = fmaf(xb4.x, xb4.x, nx); nx = fmaf(xb4.y, xb4.y, nx);
            nx = fmaf(xb4.z, xb4.z, nx); nx = fmaf(xb4.w, xb4.w, nx);
            dA = fmaf(xa.x, cA0.x, dA);  dA = fmaf(xa.y, cA0.y, dA);
            dA = fmaf(xa.z, cA0.z, dA);  dA = fmaf(xa.w, cA0.w, dA);
            dA = fmaf(xb4.x, cA1.x, dA); dA = fmaf(xb4.y, cA1.y, dA);
            dA = fmaf(xb4.z, cA1.z, dA); dA = fmaf(xb4.w, cA1.w, dA);
            dB = fmaf(xa.x, cB0.x, dB);  dB = fmaf(xa.y, cB0.y, dB);
            dB = fmaf(xa.z, cB0.z, dB);  dB = fmaf(xa.w, cB0.w, dB);
            dB = fmaf(xb4.x, cB1.x, dB); dB = fmaf(xb4.y, cB1.y, dB);
            dB = fmaf(xb4.z, cB1.z, dB); dB = fmaf(xb4.w, cB1.w, dB);
            float qA = fmaf(-2.f, dA, nx);
            float qB = fmaf(-2.f, dB, nx);
            qA = sum16(qA);
            qB = sum16(qB);
            if (dg == 0) {
                sc_lds[p][n][k0]     = qA;
                sc_lds[p][n][k0 + 1] = qB;
            }
        }
        __syncthreads();
        {
            const int row = tid >> 5;
            const int q   = tid & 31;
            float sq = sc_lds[p][row][q];
            float s  = sqrtf(fmaxf(sq + cn2_lds[q], 0.f)) * sclq;
            float m = max16(s);
            m = fmaxf(m, __shfl_xor(m, 16));
            float e = exp2f((s - m) * 1.44269504088896f);
            float sum = sum16(e);
            sum += __shfl_xor(sum, 16);
            w_lds[p][row][q] = e * (1.0f / sum);
        }
        __syncthreads();
        #pragma unroll
        for (int n = 0; n < 8; ++n) {
            const float2 w = *reinterpret_cast<const float2*>(&w_lds[p][n][k0]);
            const float4 xa = xr[n][0];
            const float4 xb4 = xr[n][1];
            tA0.x = fmaf(w.x, xa.x, tA0.x);
            tA0.y = fmaf(w.x, xa.y, tA0.y);
            tA0.z = fmaf(w.x, xa.z, tA0.z);
            tA0.w = fmaf(w.x, xa.w, tA0.w);
            tA1.x = fmaf(w.x, xb4.x, tA1.x);
            tA1.y = fmaf(w.x, xb4.y, tA1.y);
            tA1.z = fmaf(w.x, xb4.z, tA1.z);
            tA1.w = fmaf(w.x, xb4.w, tA1.w);
            tB0.x = fmaf(w.y, xa.x, tB0.x);
            tB0.y = fmaf(w.y, xa.y, tB0.y);
            tB0.z = fmaf(w.y, xa.z, tB0.z);
            tB0.w = fmaf(w.y, xa.w, tB0.w);
            tB1.x = fmaf(w.y, xb4.x, tB1.x);
            tB1.y = fmaf(w.y, xb4.y, tB1.y);
            tB1.z = fmaf(w.y, xb4.z, tB1.z);
            tB1.w = fmaf(w.y, xb4.w, tB1.w);
            swA += w.x;
            swB += w.y;
        }
    }

    float* o = ws + (long)blockIdx.x * (K * D) + k0 * D + d4;
    *reinterpret_cast<float4*>(o)       = make_float4(tA0.x - swA * cA0.x, tA0.y - swA * cA0.y,
                                                      tA0.z - swA * cA0.z, tA0.w - swA * cA0.w);
    *reinterpret_cast<float4*>(o + 64)  = make_float4(tA1.x - swA * cA1.x, tA1.y - swA * cA1.y,
                                                      tA1.z - swA * cA1.z, tA1.w - swA * cA1.w);
    *reinterpret_cast<float4*>(o + 128) = make_float4(tB0.x - swB * cB0.x, tB0.y - swB * cB0.y,
                                                      tB0.z - swB * cB0.z, tB0.w - swB * cB0.w);
    *reinterpret_cast<float4*>(o + 192) = make_float4(tB1.x - swB * cB1.x, tB1.y - swB * cB1.y,
                                                      tB1.z - swB * cB1.z, tB1.w - swB * cB1.w);
}

extern "C" void kernel_launch(void* const* d_in, const int* in_sizes, int n_in,
                              void* d_out, int out_size, void* d_ws, size_t ws_size,
                              hipStream_t stream) {
    const float* x     = (const float*)d_in[0];
    const float* codes = (const float*)d_in[1];
    const float* scale = (const float*)d_in[2];
    float* out = (float*)d_out;
    float* ws  = (float*)d_ws;

    if (ws_size >= (size_t)512 * K * D * sizeof(float)) {
        enc_partial<<<512, 256, 0, stream>>>(x, codes, scale, ws);
        reduce2<<<256, 256, 0, stream>>>(ws, out, 512);
    } else {
        const int grid1 = 128;                         // 2 MB ws fallback
        enc_partial_small<<<grid1, 256, 0, stream>>>(x, codes, scale, ws, N / (grid1 * 8));
        reduce2<<<256, 256, 0, stream>>>(ws, out, grid1);
    }
}

// Round 21
// 24.178 us; speedup vs baseline: 2.4788x; 1.0341x over previous
//
#include <hip/hip_runtime.h>

// Problem constants (fixed by the reference)
constexpr int N    = 16384;
constexpr int K    = 32;
constexpr int D    = 128;
constexpr int SPAD = K + 2;       // LDS score row stride (34)

typedef float f4 __attribute__((ext_vector_type(4)));

// ---- DPP helpers: butterfly reduce over 16-lane groups, pure VALU ----
template <int CTRL>
__device__ __forceinline__ float dpp_add(float v) {
    int j = __builtin_amdgcn_update_dpp(0, __float_as_int(v), CTRL, 0xF, 0xF, false);
    return v + __int_as_float(j);
}
template <int CTRL>
__device__ __forceinline__ float dpp_max(float v) {
    int j = __builtin_amdgcn_update_dpp(0, __float_as_int(v), CTRL, 0xF, 0xF, false);
    return fmaxf(v, __int_as_float(j));
}
__device__ __forceinline__ float sum16(float v) {
    v = dpp_add<0xB1>(v);    // quad_perm xor1
    v = dpp_add<0x4E>(v);    // quad_perm xor2
    v = dpp_add<0x141>(v);   // row_half_mirror
    v = dpp_add<0x140>(v);   // row_mirror
    return v;
}
__device__ __forceinline__ float max16(float v) {
    v = dpp_max<0xB1>(v);
    v = dpp_max<0x4E>(v);
    v = dpp_max<0x141>(v);
    v = dpp_max<0x140>(v);
    return v;
}

// ------------------------------------------------------------------
// Stage 1 (R14, measured best 24.2 us total): grid1=512, 32 rows per
// block in 4 chunks of 8 reg-resident rows. dist^2 via dot-product
// algebra; DPP softmax; double-buffered score/weight LDS; plain
// cached ws stores (NT hints cost ~3 us — R11 vs R13).
// ------------------------------------------------------------------
__global__ __launch_bounds__(256, 4) void enc_partial(
    const float* __restrict__ x,      // (N, D)
    const float* __restrict__ codes,  // (K, D)
    const float* __restrict__ scale,  // (K,)
    float* __restrict__ ws,           // (grid1, K*D)
    int nchunk)
{
    __shared__ float sc_lds[2][8][SPAD];
    __shared__ float w_lds[2][8][SPAD];
    __shared__ float cn2_lds[K];

    const int tid = threadIdx.x;
    const int kg  = tid >> 4;
    const int dg  = tid & 15;
    const int d4  = dg << 2;
    const int k0  = kg << 1;

    const float4 cA0 = *reinterpret_cast<const float4*>(&codes[k0 * D + d4]);
    const float4 cA1 = *reinterpret_cast<const float4*>(&codes[k0 * D + 64 + d4]);
    const float4 cB0 = *reinterpret_cast<const float4*>(&codes[(k0 + 1) * D + d4]);
    const float4 cB1 = *reinterpret_cast<const float4*>(&codes[(k0 + 1) * D + 64 + d4]);

    {
        float pa = 0.f, pb = 0.f;
        pa = fmaf(cA0.x, cA0.x, pa); pa = fmaf(cA0.y, cA0.y, pa);
        pa = fmaf(cA0.z, cA0.z, pa); pa = fmaf(cA0.w, cA0.w, pa);
        pa = fmaf(cA1.x, cA1.x, pa); pa = fmaf(cA1.y, cA1.y, pa);
        pa = fmaf(cA1.z, cA1.z, pa); pa = fmaf(cA1.w, cA1.w, pa);
        pb = fmaf(cB0.x, cB0.x, pb); pb = fmaf(cB0.y, cB0.y, pb);
        pb = fmaf(cB0.z, cB0.z, pb); pb = fmaf(cB0.w, cB0.w, pb);
        pb = fmaf(cB1.x, cB1.x, pb); pb = fmaf(cB1.y, cB1.y, pb);
        pb = fmaf(cB1.z, cB1.z, pb); pb = fmaf(cB1.w, cB1.w, pb);
        float cn2A = sum16(pa);
        float cn2B = sum16(pb);
        if (dg == 0) {
            cn2_lds[k0]     = cn2A;
            cn2_lds[k0 + 1] = cn2B;
        }
    }
    const float sclq = scale[tid & 31];

    float4 tA0 = make_float4(0.f, 0.f, 0.f, 0.f);
    float4 tA1 = tA0, tB0 = tA0, tB1 = tA0;
    float swA = 0.f, swB = 0.f;

    const float* xb = x + (long)blockIdx.x * nchunk * 8 * D;

    for (int c = 0; c < nchunk; ++c) {
        const int p = c & 1;
        float4 xr[8][2];
        const float* xc = xb + c * 8 * D;
        #pragma unroll
        for (int n = 0; n < 8; ++n) {
            xr[n][0] = *reinterpret_cast<const float4*>(xc + n * D + d4);
            xr[n][1] = *reinterpret_cast<const float4*>(xc + n * D + 64 + d4);
        }

        #pragma unroll
        for (int n = 0; n < 8; ++n) {
            const float4 xa = xr[n][0];
            const float4 xb4 = xr[n][1];
            float nx = 0.f, dA = 0.f, dB = 0.f;
            nx = fmaf(xa.x, xa.x, nx);   nx = fmaf(xa.y, xa.y, nx);
            nx = fmaf(xa.z, xa.z, nx);   nx = fmaf(xa.w, xa.w, nx);
            nx = fmaf(xb4.x, xb4.x, nx); nx = fmaf(xb4.y, xb4.y, nx);
            nx = fmaf(xb4.z, xb4.z, nx); nx = fmaf(xb4.w, xb4.w, nx);
            dA = fmaf(xa.x, cA0.x, dA);  dA = fmaf(xa.y, cA0.y, dA);
            dA = fmaf(xa.z, cA0.z, dA);  dA = fmaf(xa.w, cA0.w, dA);
            dA = fmaf(xb4.x, cA1.x, dA); dA = fmaf(xb4.y, cA1.y, dA);
            dA = fmaf(xb4.z, cA1.z, dA); dA = fmaf(xb4.w, cA1.w, dA);
            dB = fmaf(xa.x, cB0.x, dB);  dB = fmaf(xa.y, cB0.y, dB);
            dB = fmaf(xa.z, cB0.z, dB);  dB = fmaf(xa.w, cB0.w, dB);
            dB = fmaf(xb4.x, cB1.x, dB); dB = fmaf(xb4.y, cB1.y, dB);
            dB = fmaf(xb4.z, cB1.z, dB); dB = fmaf(xb4.w, cB1.w, dB);
            float qA = fmaf(-2.f, dA, nx);
            float qB = fmaf(-2.f, dB, nx);
            qA = sum16(qA);
            qB = sum16(qB);
            if (dg == 0) {
                sc_lds[p][n][k0]     = qA;
                sc_lds[p][n][k0 + 1] = qB;
            }
        }
        __syncthreads();

        {
            const int row = tid >> 5;
            const int q   = tid & 31;
            float sq = sc_lds[p][row][q];
            float s  = sqrtf(fmaxf(sq + cn2_lds[q], 0.f)) * sclq;
            float m = max16(s);
            m = fmaxf(m, __shfl_xor(m, 16));
            float e = exp2f((s - m) * 1.44269504088896f);
            float sum = sum16(e);
            sum += __shfl_xor(sum, 16);
            w_lds[p][row][q] = e * (1.0f / sum);
        }
        __syncthreads();

        #pragma unroll
        for (int n = 0; n < 8; ++n) {
            const float2 w = *reinterpret_cast<const float2*>(&w_lds[p][n][k0]);
            const float4 xa = xr[n][0];
            const float4 xb4 = xr[n][1];
            tA0.x = fmaf(w.x, xa.x, tA0.x);
            tA0.y = fmaf(w.x, xa.y, tA0.y);
            tA0.z = fmaf(w.x, xa.z, tA0.z);
            tA0.w = fmaf(w.x, xa.w, tA0.w);
            tA1.x = fmaf(w.x, xb4.x, tA1.x);
            tA1.y = fmaf(w.x, xb4.y, tA1.y);
            tA1.z = fmaf(w.x, xb4.z, tA1.z);
            tA1.w = fmaf(w.x, xb4.w, tA1.w);
            tB0.x = fmaf(w.y, xa.x, tB0.x);
            tB0.y = fmaf(w.y, xa.y, tB0.y);
            tB0.z = fmaf(w.y, xa.z, tB0.z);
            tB0.w = fmaf(w.y, xa.w, tB0.w);
            tB1.x = fmaf(w.y, xb4.x, tB1.x);
            tB1.y = fmaf(w.y, xb4.y, tB1.y);
            tB1.z = fmaf(w.y, xb4.z, tB1.z);
            tB1.w = fmaf(w.y, xb4.w, tB1.w);
            swA += w.x;
            swB += w.y;
        }
    }

    // ---- Epilogue: plain cached stores (keep ws in L2/L3) ----
    float* o = ws + (long)blockIdx.x * (K * D) + k0 * D + d4;
    *reinterpret_cast<float4*>(o)       = make_float4(tA0.x - swA * cA0.x, tA0.y - swA * cA0.y,
                                                      tA0.z - swA * cA0.z, tA0.w - swA * cA0.w);
    *reinterpret_cast<float4*>(o + 64)  = make_float4(tA1.x - swA * cA1.x, tA1.y - swA * cA1.y,
                                                      tA1.z - swA * cA1.z, tA1.w - swA * cA1.w);
    *reinterpret_cast<float4*>(o + 128) = make_float4(tB0.x - swB * cB0.x, tB0.y - swB * cB0.y,
                                                      tB0.z - swB * cB0.z, tB0.w - swB * cB0.w);
    *reinterpret_cast<float4*>(o + 192) = make_float4(tB1.x - swB * cB1.x, tB1.y - swB * cB1.y,
                                                      tB1.z - swB * cB1.z, tB1.w - swB * cB1.w);
}

// ------------------------------------------------------------------
// Stage 2 (R14): column-sum ws[nrows][4096] -> out[4096].
// 256 blocks; plain cached loads; unroll ILP; LDS tree; one store.
// ------------------------------------------------------------------
__global__ __launch_bounds__(256) void reduce2(
    const float* __restrict__ ws, float* __restrict__ out, int nrows)
{
    __shared__ f4 part[64][4];

    const int tid   = threadIdx.x;
    const int col   = tid & 3;
    const int slice = tid >> 2;                  // 0..63
    const int gcol  = blockIdx.x * 4 + col;      // 0..1023
    const int rpt   = nrows >> 6;                // rows per thread

    const f4* P = reinterpret_cast<const f4*>(ws);
    f4 acc0 = { 0.f, 0.f, 0.f, 0.f };
    f4 acc1 = acc0;
    long base = (long)slice * rpt * 1024 + gcol;
    #pragma unroll 4
    for (int r = 0; r < rpt; r += 2) {
        acc0 += P[base + (long)r * 1024];
        acc1 += P[base + (long)(r + 1) * 1024];
    }
    part[slice][col] = acc0 + acc1;
    __syncthreads();

    #pragma unroll
    for (int stride = 32; stride >= 1; stride >>= 1) {
        if (tid < stride * 4) {
            part[slice][col] += part[slice + stride][col];
        }
        __syncthreads();
    }
    if (tid < 4) {
        reinterpret_cast<f4*>(out)[blockIdx.x * 4 + tid] = part[0][tid];
    }
}

extern "C" void kernel_launch(void* const* d_in, const int* in_sizes, int n_in,
                              void* d_out, int out_size, void* d_ws, size_t ws_size,
                              hipStream_t stream) {
    const float* x     = (const float*)d_in[0];
    const float* codes = (const float*)d_in[1];
    const float* scale = (const float*)d_in[2];
    float* out = (float*)d_out;
    float* ws  = (float*)d_ws;

    // grid1 must divide N/8 and be a multiple of 64 (for reduce2).
    int grid1 = 512;                                   // 8 MB ws
    if (ws_size < (size_t)grid1 * K * D * sizeof(float)) grid1 = 128;   // 2 MB
    const int nchunk = N / (grid1 * 8);

    enc_partial<<<grid1, 256, 0, stream>>>(x, codes, scale, ws, nchunk);
    reduce2<<<256, 256, 0, stream>>>(ws, out, grid1);
}